// Round 1
// baseline (835.479 us; speedup 1.0000x reference)
//
#include <hip/hip_runtime.h>

#define NUM_HEADS 32
#define HEAD_DIM 128
#define ROPE_DIM 64

// One block per token, 256 threads.
// Rope region (dims 0..63 of each head): 32 heads * 8 float4-pairs = 256 pairs,
//   one per thread. Each pair is (x1 quad at d, x2 quad at d+32); both outputs
//   computed from one load each -> every byte read exactly once.
// Pass-through region (dims 64..127): 32 heads * 16 float4 = 512 copies,
//   2 per thread, coalesced.
__global__ __launch_bounds__(256) void ApplyRotary_27814208209209_kernel(
    const float* __restrict__ in,
    const float* __restrict__ sin_cache,
    const float* __restrict__ cos_cache,
    const int* __restrict__ cu_seqlen,
    int n_cu,
    float* __restrict__ out)
{
    const int t = blockIdx.x;

    // within-segment offset: linear scan over tiny cu array (wave-uniform)
    int seg = 0;
    while (seg + 1 < n_cu - 1 && cu_seqlen[seg + 1] <= t) seg++;
    const int off = t - cu_seqlen[seg];

    const int tid = threadIdx.x;

    const float4* in4  = (const float4*)(in  + (size_t)t * NUM_HEADS * HEAD_DIM);
    float4*       out4 = (float4*)      (out + (size_t)t * NUM_HEADS * HEAD_DIM);
    const float4* sin4 = (const float4*)(sin_cache + (size_t)off * ROPE_DIM);
    const float4* cos4 = (const float4*)(cos_cache + (size_t)off * ROPE_DIM);

    // ---- rope pairs ----
    {
        const int h = tid >> 3;        // head 0..31
        const int p = tid & 7;         // quad 0..7 -> dims [4p, 4p+3]
        const int base = h * (HEAD_DIM / 4);   // float4 index of head start

        const float4 a = in4[base + p];        // x1 quad: dims 4p..4p+3
        const float4 b = in4[base + p + 8];    // x2 quad: dims 4p+32..

        const float4 s1 = sin4[p];
        const float4 c1 = cos4[p];
        const float4 s2 = sin4[p + 8];
        const float4 c2 = cos4[p + 8];

        float4 oa, ob;
        // out[d]      = -x2[d]*sin[d]    + x1[d]*cos[d]        (d in [0,32))
        oa.x = fmaf(-b.x, s1.x, a.x * c1.x);
        oa.y = fmaf(-b.y, s1.y, a.y * c1.y);
        oa.z = fmaf(-b.z, s1.z, a.z * c1.z);
        oa.w = fmaf(-b.w, s1.w, a.w * c1.w);
        // out[d+32]   =  x1[d]*sin[d+32] + x2[d]*cos[d+32]
        ob.x = fmaf(a.x, s2.x, b.x * c2.x);
        ob.y = fmaf(a.y, s2.y, b.y * c2.y);
        ob.z = fmaf(a.z, s2.z, b.z * c2.z);
        ob.w = fmaf(a.w, s2.w, b.w * c2.w);

        out4[base + p]     = oa;
        out4[base + p + 8] = ob;
    }

    // ---- pass-through dims 64..127 ----
    #pragma unroll
    for (int j = tid; j < NUM_HEADS * (HEAD_DIM - ROPE_DIM) / 4; j += 256) {
        const int h = j >> 4;          // 16 float4 per head in pass region
        const int q = j & 15;
        const int idx = h * (HEAD_DIM / 4) + (ROPE_DIM / 4) + q;
        out4[idx] = in4[idx];
    }
}

extern "C" void kernel_launch(void* const* d_in, const int* in_sizes, int n_in,
                              void* d_out, int out_size, void* d_ws, size_t ws_size,
                              hipStream_t stream) {
    const float* in        = (const float*)d_in[0];
    const float* sin_cache = (const float*)d_in[1];
    const float* cos_cache = (const float*)d_in[2];
    const int*   cu        = (const int*)d_in[3];
    const int    n_cu      = in_sizes[3];

    const int total_tokens = in_sizes[0] / (NUM_HEADS * HEAD_DIM);

    ApplyRotary_27814208209209_kernel<<<total_tokens, 256, 0, stream>>>(
        in, sin_cache, cos_cache, cu, n_cu + 1 /* guard uses n_cu-1 */, (float*)d_out);
}